// Round 12
// baseline (191.236 us; speedup 1.0000x reference)
//
#include <hip/hip_runtime.h>
#include <stdint.h>

typedef unsigned long long u64;

#define PADW 134
#define WPR 3                        // 3 u64 words per 134-voxel row
#define ROWS_PER_B (PADW * PADW)     // 17,956 rows per batch
#define WPB (ROWS_PER_B * WPR)       // 53,868 words per batch
#define NBATCH 2
#define NROWS (NBATCH * ROWS_PER_B)  // 35,912
#define NWORDS (NBATCH * WPB)        // 107,736
#define NV 128
#define NV3 (NV * NV * NV)
#define PAD 3
#define RBLK 512                     // stage-1 reduction blocks
#define TS 16                        // skevo tile size (z,y)

// Bit i of word j in row (z,y) = voxel x = j*64+i. Invariant: all STORED buffers
// (X, E*, S*) have invalid bits (word 2 bits 6..63) == 0.

__device__ __forceinline__ bool inR(int v) { return (unsigned)v < (unsigned)PADW; }

__device__ __forceinline__ void loadRow(const u64* __restrict__ B, int z, int y, u64 r[3]) {
  const u64* p = B + (z * PADW + y) * WPR;
  r[0] = p[0]; r[1] = p[1]; r[2] = p[2];
}

// checked read: OOB row -> zeros + false (dil OR-identity)
__device__ __forceinline__ bool rowRead(const u64* __restrict__ B, int gz, int gy, u64 r[3]) {
  if (!inR(gz) || !inR(gy)) { r[0] = r[1] = r[2] = 0ULL; return false; }
  loadRow(B, gz, gy, r);
  return true;
}

// d |= horizontal 3-dilation of full row r (OOB x -> 0)
__device__ __forceinline__ void orHdil(const u64 r[3], u64 d[3]) {
  d[0] |= r[0] | (r[0] << 1) | ((r[0] >> 1) | (r[1] << 63));
  d[1] |= r[1] | ((r[1] << 1) | (r[0] >> 63)) | ((r[1] >> 1) | (r[2] << 63));
  d[2] |= r[2] | ((r[2] << 1) | (r[1] >> 63)) | (r[2] >> 1);
}

// full-row horizontal 3-erosion (OOB x -> 1 edge rules); clean if c clean
__device__ __forceinline__ void eroX(const u64 c[3], u64 e[3]) {
  e[0] = c[0] & ((c[0] << 1) | 1ULL)         & ((c[0] >> 1) | (c[1] << 63));
  e[1] = c[1] & ((c[1] << 1) | (c[0] >> 63)) & ((c[1] >> 1) | (c[2] << 63));
  e[2] = c[2] & ((c[2] << 1) | (c[1] >> 63)) & ((c[2] >> 1) | (1ULL << 5));
}

// ero6 of stored buffer at (gz,gy); OOB center -> ~0 (AND identity marker)
__device__ __forceinline__ void eroAt(const u64* __restrict__ Bb, int gz, int gy, u64 e[3]) {
  if (!inR(gz) || !inR(gy)) { e[0] = e[1] = e[2] = ~0ULL; return; }
  u64 c[3], n[3];
  loadRow(Bb, gz, gy, c);
  eroX(c, e);
  if (inR(gy - 1)) { loadRow(Bb, gz, gy - 1, n); e[0] &= n[0]; e[1] &= n[1]; e[2] &= n[2]; }
  if (inR(gy + 1)) { loadRow(Bb, gz, gy + 1, n); e[0] &= n[0]; e[1] &= n[1]; e[2] &= n[2]; }
  if (inR(gz - 1)) { loadRow(Bb, gz - 1, gy, n); e[0] &= n[0]; e[1] &= n[1]; e[2] &= n[2]; }
  if (inR(gz + 1)) { loadRow(Bb, gz + 1, gy, n); e[0] &= n[0]; e[1] &= n[1]; e[2] &= n[2]; }
}

// ero6 from register rows (neighbors may be ~0 identity markers)
__device__ __forceinline__ void eroReg(const u64 c[3], const u64 ym[3], const u64 yp[3],
                                       const u64 zm[3], const u64 zp[3], u64 e[3]) {
  eroX(c, e);
  e[0] &= ym[0] & yp[0] & zm[0] & zp[0];
  e[1] &= ym[1] & yp[1] & zm[1] & zp[1];
  e[2] &= ym[2] & yp[2] & zm[2] & zp[2];
}

// ---------------------------------------------------------------- binarize + pad + pack
__global__ void binpack_k(const float* __restrict__ logit, u64* __restrict__ X) {
  int wid = (blockIdx.x * blockDim.x + threadIdx.x) >> 6;
  int lane = threadIdx.x & 63;
  if (wid >= NROWS) return;
  int b = wid / ROWS_PER_B;
  int r = wid - b * ROWS_PER_B;
  int z = r / PADW;
  int y = r - z * PADW;
  bool padrow = (z < PAD || z >= PAD + NV || y < PAD || y >= PAD + NV);
  const float TH = 0.84729786f;  // ln(0.7/0.3): sigmoid(l)>0.7 <=> l>TH
  u64* rowp = X + (size_t)b * WPB + (z * PADW + y) * WPR;
#pragma unroll
  for (int j = 0; j < WPR; ++j) {
    int x = j * 64 + lane;
    bool pred = false;
    if (x < PADW) {
      if (padrow || x < PAD || x >= PAD + NV) {
        pred = true;  // pad voxel = 1
      } else {
        float l = logit[(((size_t)b * NV + (z - PAD)) * NV + (y - PAD)) * NV + (x - PAD)];
        pred = l > TH;
      }
    }
    u64 w = __ballot(pred);
    if (lane == 0) rowp[j] = w;
  }
}

// ---------------------------------------------------------------- erosion chain:
// o1=ero6(in), o2=ero6^2(in), o3=ero6^3(in) — per-thread diamond, registers only
__global__ __launch_bounds__(256) void chain3_k(const u64* __restrict__ in,
                                                u64* __restrict__ o1,
                                                u64* __restrict__ o2,
                                                u64* __restrict__ o3) {
  int rid = blockIdx.x * 256 + threadIdx.x;
  if (rid >= NROWS) return;
  int b = rid / ROWS_PER_B;
  int rr = rid - b * ROWS_PER_B;
  int z = rr / PADW;
  int y = rr - (rr / PADW) * PADW;
  const u64* Bb = in + (size_t)b * WPB;

  u64 e1[5][5][3];  // diamond<=2 positions only (static unrolled indices -> registers)
#pragma unroll
  for (int dz = -2; dz <= 2; ++dz) {
#pragma unroll
    for (int dy = -2; dy <= 2; ++dy) {
      int ad = (dz < 0 ? -dz : dz) + (dy < 0 ? -dy : dy);
      if (ad > 2) continue;
      eroAt(Bb, z + dz, y + dy, e1[dz + 2][dy + 2]);
    }
  }
  u64 e2[3][3][3];
#pragma unroll
  for (int dz = -1; dz <= 1; ++dz) {
#pragma unroll
    for (int dy = -1; dy <= 1; ++dy) {
      int ad = (dz < 0 ? -dz : dz) + (dy < 0 ? -dy : dy);
      if (ad > 1) continue;
      if (!inR(z + dz) || !inR(y + dy)) {
        e2[dz + 1][dy + 1][0] = e2[dz + 1][dy + 1][1] = e2[dz + 1][dy + 1][2] = ~0ULL;
      } else {
        eroReg(e1[dz + 2][dy + 2], e1[dz + 2][dy + 1], e1[dz + 2][dy + 3],
               e1[dz + 1][dy + 2], e1[dz + 3][dy + 2], e2[dz + 1][dy + 1]);
      }
    }
  }
  u64 e3[3];
  eroReg(e2[1][1], e2[1][0], e2[1][2], e2[0][1], e2[2][1], e3);

  size_t off = (size_t)b * WPB + (z * PADW + y) * WPR;
  o1[off + 0] = e1[2][2][0]; o1[off + 1] = e1[2][2][1]; o1[off + 2] = e1[2][2][2];
  o2[off + 0] = e2[1][1][0]; o2[off + 1] = e2[1][1][1]; o2[off + 2] = e2[1][1][2];
  o3[off + 0] = e3[0];       o3[off + 1] = e3[1];       o3[off + 2] = e3[2];
}

// ---------------------------------------------------------------- fused sk-evolution:
// S0 = E0 & ~dil26(E1); S_t = (E_t & ~dil26(E_{t+1})) | S_{t-1} | (E_{t-1} & dil26(S_{t-1}))
// E-chain from global (fully valid); only S double-buffered in LDS. Halo = ITERS.
struct EPtrs { const u64* p[7]; };

template<int ITERS>
__global__ __launch_bounds__(512) void skevo_k(EPtrs eps, u64* __restrict__ Sg) {
  constexpr int H = ITERS;
  constexpr int SW = TS + 2 * H;
  constexpr int R = SW * SW;
  __shared__ u64 lds[2][R][3];  // ITERS=5: 32.4 KB; ITERS=2: 19.2 KB
  const int nt = (PADW + TS - 1) / TS;  // 9
  int b = blockIdx.x / (nt * nt);
  int t = blockIdx.x - b * (nt * nt);
  int z0 = (t / nt) * TS - H;
  int y0 = (t - (t / nt) * nt) * TS - H;
  size_t boff = (size_t)b * WPB;

  // init: S = E0 & ~dil26(E1); out-of-volume rows -> 0 (exact dil identity)
  for (int ir = threadIdx.x; ir < R; ir += 512) {
    int gz = z0 + ir / SW, gy = y0 + ir % SW;
    u64 d[3] = {0, 0, 0}, rr[3], c[3];
#pragma unroll
    for (int dz = -1; dz <= 1; ++dz)
#pragma unroll
      for (int dy = -1; dy <= 1; ++dy)
        if (rowRead(eps.p[1] + boff, gz + dz, gy + dy, rr)) orHdil(rr, d);
    rowRead(eps.p[0] + boff, gz, gy, c);  // OOB -> zeros
    lds[0][ir][0] = c[0] & ~d[0];
    lds[0][ir][1] = c[1] & ~d[1];
    lds[0][ir][2] = c[2] & ~d[2];
  }
  __syncthreads();

  int cur = 0;
#pragma unroll
  for (int it = 1; it <= ITERS; ++it) {  // unrolled -> eps.p[it] static (rule #20)
    for (int ir = threadIdx.x; ir < R; ir += 512) {
      int iz = ir / SW, iy = ir - (ir / SW) * SW;
      int gz = z0 + iz, gy = y0 + iy;
      u64 dE[3] = {0, 0, 0}, dS[3] = {0, 0, 0}, rr[3];
#pragma unroll
      for (int dz = -1; dz <= 1; ++dz) {
#pragma unroll
        for (int dy = -1; dy <= 1; ++dy) {
          if (rowRead(eps.p[it + 1] + boff, gz + dz, gy + dy, rr)) orHdil(rr, dE);
          int jz = iz + dz, jy = iy + dy;
          if (jz >= 0 && jz < SW && jy >= 0 && jy < SW) {
            u64 sr[3];
            sr[0] = lds[cur][jz * SW + jy][0];
            sr[1] = lds[cur][jz * SW + jy][1];
            sr[2] = lds[cur][jz * SW + jy][2];
            orHdil(sr, dS);
          }
        }
      }
      u64 ec[3], xc[3];
      rowRead(eps.p[it] + boff, gz, gy, ec);      // OOB -> 0
      rowRead(eps.p[it - 1] + boff, gz, gy, xc);  // OOB -> 0
      u64 s0 = lds[cur][ir][0], s1 = lds[cur][ir][1], s2 = lds[cur][ir][2];
      lds[cur ^ 1][ir][0] = (ec[0] & ~dE[0]) | s0 | (xc[0] & dS[0]);
      lds[cur ^ 1][ir][1] = (ec[1] & ~dE[1]) | s1 | (xc[1] & dS[1]);
      lds[cur ^ 1][ir][2] = (ec[2] & ~dE[2]) | s2 | (xc[2] & dS[2]);
    }
    __syncthreads();
    cur ^= 1;
  }

  // write center tile
  for (int ir = threadIdx.x; ir < R; ir += 512) {
    int iz = ir / SW, iy = ir - (ir / SW) * SW;
    if (iz < H || iz >= H + TS || iy < H || iy >= H + TS) continue;
    int gz = z0 + iz, gy = y0 + iy;
    if (!inR(gz) || !inR(gy)) continue;
    u64* o = Sg + boff + (gz * PADW + gy) * WPR;
    o[0] = lds[cur][ir][0];
    o[1] = lds[cur][ir][1];
    o[2] = lds[cur][ir][2];
  }
}

// ---------------------------------------------------------------- reduction stage 1 (no atomics)
__global__ __launch_bounds__(256) void reduce1_k(const float* __restrict__ logit,
                                                 const float* __restrict__ vcl,
                                                 const u64* __restrict__ S,
                                                 float* __restrict__ partials) {
  int tid = blockIdx.x * 256 + threadIdx.x;
  float p[8];
#pragma unroll
  for (int k = 0; k < 8; ++k) p[k] = 0.f;
  for (int s = tid; s < NV3 / 4; s += RBLK * 256) {
    int i = s << 2;
    int z = i >> 14, y = (i >> 7) & 127, x = i & 127;
#pragma unroll
    for (int b = 0; b < NBATCH; ++b) {
      float4 lv = ((const float4*)(logit + (size_t)b * NV3))[s];
      float4 cv = ((const float4*)(vcl + (size_t)b * NV3))[s];
      const u64* rowp = S + (size_t)b * WPB + ((size_t)(z + PAD) * PADW + (y + PAD)) * WPR;
      float lf[4] = {lv.x, lv.y, lv.z, lv.w};
      float cf[4] = {cv.x, cv.y, cv.z, cv.w};
#pragma unroll
      for (int k = 0; k < 4; ++k) {
        float vp = 1.0f / (1.0f + expf(-lf[k]));
        int xp = x + k + PAD;
        u64 w = rowp[xp >> 6];
        float sv = (float)((w >> (xp & 63)) & 1ULL);
        float c = cf[k];
        p[b * 4 + 0] += vp * c;
        p[b * 4 + 1] += c;
        p[b * 4 + 2] += c * vp * sv;
        p[b * 4 + 3] += vp * sv;
      }
    }
  }
#pragma unroll
  for (int k = 0; k < 8; ++k)
    for (int off = 32; off > 0; off >>= 1) p[k] += __shfl_down(p[k], off);
  __shared__ float ls[4][8];
  int wid = threadIdx.x >> 6, lane = threadIdx.x & 63;
  if (lane == 0) {
#pragma unroll
    for (int k = 0; k < 8; ++k) ls[wid][k] = p[k];
  }
  __syncthreads();
  if (threadIdx.x == 0) {
#pragma unroll
    for (int k = 0; k < 8; ++k)
      partials[k * RBLK + blockIdx.x] = ls[0][k] + ls[1][k] + ls[2][k] + ls[3][k];
  }
}

// ---------------------------------------------------------------- reduction stage 2 + loss
__global__ void finalize2_k(const float* __restrict__ partials, float* __restrict__ out) {
  int t = threadIdx.x;  // 512 threads
  double s[8];
#pragma unroll
  for (int k = 0; k < 8; ++k) s[k] = (double)partials[k * RBLK + t];
#pragma unroll
  for (int k = 0; k < 8; ++k)
    for (int off = 32; off > 0; off >>= 1) s[k] += __shfl_down(s[k], off);
  __shared__ double ls[8][8];
  int wid = t >> 6, lane = t & 63;
  if (lane == 0) {
#pragma unroll
    for (int k = 0; k < 8; ++k) ls[k][wid] = s[k];
  }
  __syncthreads();
  if (t == 0) {
    double a[8];
#pragma unroll
    for (int k = 0; k < 8; ++k) {
      a[k] = 0.0;
      for (int w = 0; w < 8; ++w) a[k] += ls[k][w];
    }
    const double eps = 1e-12;
    double tp = 0.5 * ((a[0] + eps) / (a[1] + eps) + (a[4] + eps) / (a[5] + eps));
    double ts = 0.5 * ((a[2] + eps) / (a[3] + eps) + (a[6] + eps) / (a[7] + eps));
    out[0] = (float)(1.0 - (2.0 * tp * ts + eps) / (tp + ts + eps));
  }
}

// ---------------------------------------------------------------- host side
extern "C" void kernel_launch(void* const* d_in, const int* in_sizes, int n_in,
                              void* d_out, int out_size, void* d_ws, size_t ws_size,
                              hipStream_t stream) {
  const float* logit = (const float*)d_in[0];  // Vlogit
  const float* vcl = (const float*)d_in[1];    // Vcl
  // d_in[2] (Vedt) unused by the reference loss
  float* out = (float*)d_out;

  u64* base = (u64*)d_ws;
  u64* B[8];
  for (int i = 0; i < 8; ++i) B[i] = base + (size_t)i * NWORDS;
  float* partials = (float*)(base + (size_t)8 * NWORDS);  // 8*RBLK floats

  const int cBlocks = (NROWS + 255) / 256;  // 141
  const int nt = (PADW + TS - 1) / TS;      // 9
  const int sBlocks = NBATCH * nt * nt;     // 162
  const int bBlocks = (NROWS + 3) / 4;      // binpack: 4 waves/block

  binpack_k<<<bBlocks, 256, 0, stream>>>(logit, B[0]);

  // skeletonize #1 (5 iters): chain E1..E6, then fused sk-evolution
  chain3_k<<<cBlocks, 256, 0, stream>>>(B[0], B[1], B[2], B[3]);
  chain3_k<<<cBlocks, 256, 0, stream>>>(B[3], B[4], B[5], B[6]);
  EPtrs eA;
  for (int i = 0; i < 7; ++i) eA.p[i] = B[i];
  skevo_k<5><<<sBlocks, 512, 0, stream>>>(eA, B[7]);  // S1 -> B7

  // skeletonize #2 (2 iters) on S1
  chain3_k<<<cBlocks, 256, 0, stream>>>(B[7], B[1], B[2], B[3]);  // F1..F3
  EPtrs eB;
  eB.p[0] = B[7]; eB.p[1] = B[1]; eB.p[2] = B[2]; eB.p[3] = B[3];
  eB.p[4] = B[0]; eB.p[5] = B[0]; eB.p[6] = B[0];  // unused
  skevo_k<2><<<sBlocks, 512, 0, stream>>>(eB, B[4]);  // S2 -> B4

  reduce1_k<<<RBLK, 256, 0, stream>>>(logit, vcl, B[4], partials);
  finalize2_k<<<1, 512, 0, stream>>>(partials, out);
}